// Round 3
// baseline (450.346 us; speedup 1.0000x reference)
//
#include <hip/hip_runtime.h>
#include <hip/hip_bf16.h>

#define D 128
#define NC 5

__global__ __launch_bounds__(256) void bilinear_mixture_kernel(
    const float* __restrict__ u_feats,   // [NUM_USERS, 128] f32
    const float* __restrict__ v_feats,   // [NUM_ITEMS, 128] f32
    const int*   __restrict__ u_idx,     // [E]
    const int*   __restrict__ v_idx,     // [E]
    const float* __restrict__ W,         // [3, 128] f32
    const float* __restrict__ scalars,   // [3, 5] f32
    const float* __restrict__ u_bias,    // [NUM_USERS, 5] f32
    const float* __restrict__ v_bias,    // [NUM_ITEMS, 5] f32
    float* __restrict__ out,             // [E, 5] f32
    int E)
{
    const int lane = threadIdx.x & 15;   // 16 lanes per edge: 8 f32 (32B) each
    const int grp  = threadIdx.x >> 4;   // 16 edges per 256-thread block
    const int e    = blockIdx.x * 16 + grp;
    if (e >= E) return;

    const int ui = u_idx[e];
    const int vi = v_idx[e];

    // Row base pointers; rows are 512B, 16B-aligned -> float4 loads are legal.
    const float4* ur = (const float4*)(u_feats + (size_t)ui * D);
    const float4* vr = (const float4*)(v_feats + (size_t)vi * D);
    const float4* Wr = (const float4*)W;   // each W row = 128 f32 = 32 float4

    // Each lane covers elements [lane*8, lane*8+8): two float4s per row.
    float4 ua0 = ur[lane * 2 + 0];
    float4 ua1 = ur[lane * 2 + 1];
    float4 va0 = vr[lane * 2 + 0];
    float4 va1 = vr[lane * 2 + 1];
    float4 w00 = Wr[ 0 + lane * 2], w01 = Wr[ 1 + lane * 2];
    float4 w10 = Wr[32 + lane * 2], w11 = Wr[33 + lane * 2];
    float4 w20 = Wr[64 + lane * 2], w21 = Wr[65 + lane * 2];

    float s0 = 0.f, s1 = 0.f, s2 = 0.f;
    #pragma unroll
    for (int k = 0; k < 4; ++k) {
        float p = (&ua0.x)[k] * (&va0.x)[k];
        s0 = fmaf(p, (&w00.x)[k], s0);
        s1 = fmaf(p, (&w10.x)[k], s1);
        s2 = fmaf(p, (&w20.x)[k], s2);
    }
    #pragma unroll
    for (int k = 0; k < 4; ++k) {
        float p = (&ua1.x)[k] * (&va1.x)[k];
        s0 = fmaf(p, (&w01.x)[k], s0);
        s1 = fmaf(p, (&w11.x)[k], s1);
        s2 = fmaf(p, (&w21.x)[k], s2);
    }

    // Reduce the three partial dots across the 16-lane group.
    #pragma unroll
    for (int off = 8; off > 0; off >>= 1) {
        s0 += __shfl_xor(s0, off, 16);
        s1 += __shfl_xor(s1, off, 16);
        s2 += __shfl_xor(s2, off, 16);
    }

    // Lanes 0..4 each produce one class logit.
    if (lane < NC) {
        float r = s0 * scalars[0 * NC + lane]
                + s1 * scalars[1 * NC + lane]
                + s2 * scalars[2 * NC + lane]
                + u_bias[(size_t)ui * NC + lane]
                + v_bias[(size_t)vi * NC + lane];
        out[(size_t)e * NC + lane] = r;
    }
}

extern "C" void kernel_launch(void* const* d_in, const int* in_sizes, int n_in,
                              void* d_out, int out_size, void* d_ws, size_t ws_size,
                              hipStream_t stream) {
    const float* u_feats = (const float*)d_in[0];
    const float* v_feats = (const float*)d_in[1];
    const int*   u_idx   = (const int*)d_in[2];
    const int*   v_idx   = (const int*)d_in[3];
    const float* W       = (const float*)d_in[4];
    const float* scalars = (const float*)d_in[5];
    const float* u_bias  = (const float*)d_in[6];
    const float* v_bias  = (const float*)d_in[7];
    float* out           = (float*)d_out;

    const int E = in_sizes[2];
    const int edges_per_block = 256 / 16;  // 16
    const int blocks = (E + edges_per_block - 1) / edges_per_block;

    bilinear_mixture_kernel<<<blocks, 256, 0, stream>>>(
        u_feats, v_feats, u_idx, v_idx, W, scalars, u_bias, v_bias, out, E);
}

// Round 4
// 349.069 us; speedup vs baseline: 1.2901x; 1.2901x over previous
//
#include <hip/hip_runtime.h>
#include <hip/hip_bf16.h>

#define D 128
#define NC 5

typedef unsigned int u32;

__device__ __forceinline__ float bf_lo(u32 u) { return __uint_as_float(u << 16); }
__device__ __forceinline__ float bf_hi(u32 u) { return __uint_as_float(u & 0xFFFF0000u); }

// ---- Pass 1: convert f32 feature table -> bf16 (RNE), 8 elems/thread ----
__global__ __launch_bounds__(256) void cvt_f32_to_bf16_kernel(
    const float* __restrict__ src, __hip_bfloat16* __restrict__ dst, int n8)
{
    int i = blockIdx.x * 256 + threadIdx.x;            // index over groups of 8
    if (i >= n8) return;
    const float4* s = (const float4*)src;
    float4 a = s[i * 2 + 0];
    float4 b = s[i * 2 + 1];
    u32 r[4];
    #pragma unroll
    for (int k = 0; k < 4; ++k) {
        float lo = (k < 2) ? (&a.x)[2 * k]     : (&b.x)[2 * (k - 2)];
        float hi = (k < 2) ? (&a.x)[2 * k + 1] : (&b.x)[2 * (k - 2) + 1];
        u32 l = __hip_bfloat16_raw(__float2bfloat16(lo)).x;
        u32 h = __hip_bfloat16_raw(__float2bfloat16(hi)).x;
        r[k] = l | (h << 16);
    }
    uint4* d = (uint4*)dst;
    d[i] = make_uint4(r[0], r[1], r[2], r[3]);
}

// ---- Pass 2: per-edge gather (bf16 rows) + diagonal bilinear + mix ----
__global__ __launch_bounds__(256) void bilinear_bf16_kernel(
    const __hip_bfloat16* __restrict__ u_bf,   // [NUM_USERS,128] bf16 (in ws)
    const __hip_bfloat16* __restrict__ v_bf,   // [NUM_ITEMS,128] bf16 (in ws)
    const int*   __restrict__ u_idx,
    const int*   __restrict__ v_idx,
    const float* __restrict__ W,               // [3,128] f32
    const float* __restrict__ scalars,         // [3,5]  f32
    const float* __restrict__ u_bias,          // [*,5]  f32
    const float* __restrict__ v_bias,          // [*,5]  f32
    float* __restrict__ out,                   // [E,5]  f32
    int E)
{
    const int lane = threadIdx.x & 15;   // 16 lanes/edge: 8 bf16 (16B) each
    const int grp  = threadIdx.x >> 4;
    const int e    = blockIdx.x * 16 + grp;
    if (e >= E) return;

    // idx arrays are streamed exactly once -> non-temporal
    const int ui = __builtin_nontemporal_load(u_idx + e);
    const int vi = __builtin_nontemporal_load(v_idx + e);

    uint4 ua = ((const uint4*)(u_bf + (size_t)ui * D))[lane];
    uint4 va = ((const uint4*)(v_bf + (size_t)vi * D))[lane];

    const float4* Wr = (const float4*)W;       // 32 float4 per row
    float4 w00 = Wr[ 0 + lane * 2], w01 = Wr[ 1 + lane * 2];
    float4 w10 = Wr[32 + lane * 2], w11 = Wr[33 + lane * 2];
    float4 w20 = Wr[64 + lane * 2], w21 = Wr[65 + lane * 2];
    const float* wv0 = &w00.x;   // w00,w01 contiguous on stack view
    const float* wv1 = &w10.x;
    const float* wv2 = &w20.x;

    float s0 = 0.f, s1 = 0.f, s2 = 0.f;
    #pragma unroll
    for (int k = 0; k < 4; ++k) {
        u32 uu = (&ua.x)[k];
        u32 vv = (&va.x)[k];
        float plo = bf_lo(uu) * bf_lo(vv);     // element 2k
        float phi = bf_hi(uu) * bf_hi(vv);     // element 2k+1
        // element 2k / 2k+1 of lane's 8-wide slice:
        float wl0 = (k < 2) ? wv0[2*k]   : (&w01.x)[2*(k-2)];
        float wh0 = (k < 2) ? wv0[2*k+1] : (&w01.x)[2*(k-2)+1];
        float wl1 = (k < 2) ? wv1[2*k]   : (&w11.x)[2*(k-2)];
        float wh1 = (k < 2) ? wv1[2*k+1] : (&w11.x)[2*(k-2)+1];
        float wl2 = (k < 2) ? wv2[2*k]   : (&w21.x)[2*(k-2)];
        float wh2 = (k < 2) ? wv2[2*k+1] : (&w21.x)[2*(k-2)+1];
        s0 = fmaf(plo, wl0, s0); s0 = fmaf(phi, wh0, s0);
        s1 = fmaf(plo, wl1, s1); s1 = fmaf(phi, wh1, s1);
        s2 = fmaf(plo, wl2, s2); s2 = fmaf(phi, wh2, s2);
    }

    #pragma unroll
    for (int off = 8; off > 0; off >>= 1) {
        s0 += __shfl_xor(s0, off, 16);
        s1 += __shfl_xor(s1, off, 16);
        s2 += __shfl_xor(s2, off, 16);
    }

    if (lane < NC) {
        float r = s0 * scalars[0 * NC + lane]
                + s1 * scalars[1 * NC + lane]
                + s2 * scalars[2 * NC + lane]
                + u_bias[(size_t)ui * NC + lane]
                + v_bias[(size_t)vi * NC + lane];
        __builtin_nontemporal_store(r, out + (size_t)e * NC + lane);
    }
}

// ---- Fallback (round-3 kernel, f32 gathers) if ws too small ----
__global__ __launch_bounds__(256) void bilinear_f32_kernel(
    const float* __restrict__ u_feats, const float* __restrict__ v_feats,
    const int* __restrict__ u_idx, const int* __restrict__ v_idx,
    const float* __restrict__ W, const float* __restrict__ scalars,
    const float* __restrict__ u_bias, const float* __restrict__ v_bias,
    float* __restrict__ out, int E)
{
    const int lane = threadIdx.x & 15;
    const int grp  = threadIdx.x >> 4;
    const int e    = blockIdx.x * 16 + grp;
    if (e >= E) return;
    const int ui = u_idx[e];
    const int vi = v_idx[e];
    const float4* ur = (const float4*)(u_feats + (size_t)ui * D);
    const float4* vr = (const float4*)(v_feats + (size_t)vi * D);
    const float4* Wr = (const float4*)W;
    float4 ua0 = ur[lane*2+0], ua1 = ur[lane*2+1];
    float4 va0 = vr[lane*2+0], va1 = vr[lane*2+1];
    float4 w00 = Wr[ 0+lane*2], w01 = Wr[ 1+lane*2];
    float4 w10 = Wr[32+lane*2], w11 = Wr[33+lane*2];
    float4 w20 = Wr[64+lane*2], w21 = Wr[65+lane*2];
    float s0=0.f, s1=0.f, s2=0.f;
    #pragma unroll
    for (int k = 0; k < 4; ++k) {
        float p = (&ua0.x)[k] * (&va0.x)[k];
        s0 = fmaf(p, (&w00.x)[k], s0);
        s1 = fmaf(p, (&w10.x)[k], s1);
        s2 = fmaf(p, (&w20.x)[k], s2);
    }
    #pragma unroll
    for (int k = 0; k < 4; ++k) {
        float p = (&ua1.x)[k] * (&va1.x)[k];
        s0 = fmaf(p, (&w01.x)[k], s0);
        s1 = fmaf(p, (&w11.x)[k], s1);
        s2 = fmaf(p, (&w21.x)[k], s2);
    }
    #pragma unroll
    for (int off = 8; off > 0; off >>= 1) {
        s0 += __shfl_xor(s0, off, 16);
        s1 += __shfl_xor(s1, off, 16);
        s2 += __shfl_xor(s2, off, 16);
    }
    if (lane < NC) {
        float r = s0*scalars[0*NC+lane] + s1*scalars[1*NC+lane] + s2*scalars[2*NC+lane]
                + u_bias[(size_t)ui*NC+lane] + v_bias[(size_t)vi*NC+lane];
        out[(size_t)e*NC+lane] = r;
    }
}

extern "C" void kernel_launch(void* const* d_in, const int* in_sizes, int n_in,
                              void* d_out, int out_size, void* d_ws, size_t ws_size,
                              hipStream_t stream) {
    const float* u_feats = (const float*)d_in[0];
    const float* v_feats = (const float*)d_in[1];
    const int*   u_idx   = (const int*)d_in[2];
    const int*   v_idx   = (const int*)d_in[3];
    const float* W       = (const float*)d_in[4];
    const float* scalars = (const float*)d_in[5];
    const float* u_bias  = (const float*)d_in[6];
    const float* v_bias  = (const float*)d_in[7];
    float* out           = (float*)d_out;

    const int nu = in_sizes[0];   // NUM_USERS * 128
    const int nv = in_sizes[1];   // NUM_ITEMS * 128
    const int E  = in_sizes[2];
    const int blocks = (E + 15) / 16;

    const size_t need = (size_t)(nu + nv) * sizeof(__hip_bfloat16);
    if (ws_size >= need) {
        __hip_bfloat16* u_bf = (__hip_bfloat16*)d_ws;
        __hip_bfloat16* v_bf = u_bf + nu;
        int nu8 = nu / 8, nv8 = nv / 8;   // D=128 divisible by 8
        cvt_f32_to_bf16_kernel<<<(nu8 + 255) / 256, 256, 0, stream>>>(u_feats, u_bf, nu8);
        cvt_f32_to_bf16_kernel<<<(nv8 + 255) / 256, 256, 0, stream>>>(v_feats, v_bf, nv8);
        bilinear_bf16_kernel<<<blocks, 256, 0, stream>>>(
            u_bf, v_bf, u_idx, v_idx, W, scalars, u_bias, v_bias, out, E);
    } else {
        bilinear_f32_kernel<<<blocks, 256, 0, stream>>>(
            u_feats, v_feats, u_idx, v_idx, W, scalars, u_bias, v_bias, out, E);
    }
}

// Round 5
// 336.878 us; speedup vs baseline: 1.3368x; 1.0362x over previous
//
#include <hip/hip_runtime.h>
#include <hip/hip_bf16.h>

#define D 128
#define NC 5

typedef unsigned int u32;

__device__ __forceinline__ float bf_lo(u32 u) { return __uint_as_float(u << 16); }
__device__ __forceinline__ float bf_hi(u32 u) { return __uint_as_float(u & 0xFFFF0000u); }

// Convert 8 consecutive f32 -> 8 bf16 (RNE), packed as one uint4.
__device__ __forceinline__ void cvt8(const float* __restrict__ src,
                                     __hip_bfloat16* __restrict__ dst, int i) {
    const float4* s = (const float4*)src;
    float4 a = s[i * 2 + 0];
    float4 b = s[i * 2 + 1];
    u32 r[4];
    #pragma unroll
    for (int k = 0; k < 4; ++k) {
        float lo = (k < 2) ? (&a.x)[2 * k]     : (&b.x)[2 * (k - 2)];
        float hi = (k < 2) ? (&a.x)[2 * k + 1] : (&b.x)[2 * (k - 2) + 1];
        u32 l = __hip_bfloat16_raw(__float2bfloat16(lo)).x;
        u32 h = __hip_bfloat16_raw(__float2bfloat16(hi)).x;
        r[k] = l | (h << 16);
    }
    ((uint4*)dst)[i] = make_uint4(r[0], r[1], r[2], r[3]);
}

// ---- Pass 1: convert u_feats, v_feats, W to bf16 in one launch ----
__global__ __launch_bounds__(256) void cvt_all_kernel(
    const float* __restrict__ u_feats, const float* __restrict__ v_feats,
    const float* __restrict__ W,
    __hip_bfloat16* __restrict__ u_bf, __hip_bfloat16* __restrict__ v_bf,
    __hip_bfloat16* __restrict__ W_bf,
    int nu8, int nv8, int nw8)
{
    int i = blockIdx.x * 256 + threadIdx.x;
    if (i < nu8) {
        cvt8(u_feats, u_bf, i);
    } else if (i < nu8 + nv8) {
        cvt8(v_feats, v_bf, i - nu8);
    } else if (i < nu8 + nv8 + nw8) {
        cvt8(W, W_bf, i - nu8 - nv8);
    }
}

__device__ __forceinline__ void dot8(uint4 u, uint4 v, uint4 w0, uint4 w1, uint4 w2,
                                     float& s0, float& s1, float& s2) {
    #pragma unroll
    for (int k = 0; k < 4; ++k) {
        u32 uu = (&u.x)[k], vv = (&v.x)[k];
        u32 a0 = (&w0.x)[k], a1 = (&w1.x)[k], a2 = (&w2.x)[k];
        float plo = bf_lo(uu) * bf_lo(vv);
        float phi = bf_hi(uu) * bf_hi(vv);
        s0 = fmaf(plo, bf_lo(a0), s0); s0 = fmaf(phi, bf_hi(a0), s0);
        s1 = fmaf(plo, bf_lo(a1), s1); s1 = fmaf(phi, bf_hi(a1), s1);
        s2 = fmaf(plo, bf_lo(a2), s2); s2 = fmaf(phi, bf_hi(a2), s2);
    }
}

// ---- Pass 2: 8 lanes/edge, 16 bf16 per lane per row (2 uint4 gathers/row) ----
__global__ __launch_bounds__(256) void bilinear_bf16_kernel(
    const __hip_bfloat16* __restrict__ u_bf,   // [NUM_USERS,128] bf16 (ws)
    const __hip_bfloat16* __restrict__ v_bf,   // [NUM_ITEMS,128] bf16 (ws)
    const __hip_bfloat16* __restrict__ W_bf,   // [3,128] bf16 (ws)
    const int*   __restrict__ u_idx,
    const int*   __restrict__ v_idx,
    const float* __restrict__ scalars,         // [3,5] f32
    const float* __restrict__ u_bias,          // [*,5] f32
    const float* __restrict__ v_bias,          // [*,5] f32
    float* __restrict__ out,                   // [E,5] f32
    int E)
{
    const int lane = threadIdx.x & 7;    // 8 lanes/edge: 16 bf16 (32B) each
    const int grp  = threadIdx.x >> 3;   // 32 edges per 256-thread block
    const int e    = blockIdx.x * 32 + grp;
    if (e >= E) return;

    const int ui = __builtin_nontemporal_load(u_idx + e);
    const int vi = __builtin_nontemporal_load(v_idx + e);

    // 4 independent row-gather loads in flight per lane.
    const uint4* ur = (const uint4*)(u_bf + (size_t)ui * D);   // 16 uint4/row
    const uint4* vr = (const uint4*)(v_bf + (size_t)vi * D);
    uint4 ua0 = ur[lane * 2 + 0];
    uint4 ua1 = ur[lane * 2 + 1];
    uint4 va0 = vr[lane * 2 + 0];
    uint4 va1 = vr[lane * 2 + 1];

    // Hoisted cached loads (overlap the gathers).
    const uint4* Wr = (const uint4*)W_bf;                      // 16 uint4/basis
    uint4 w00 = Wr[ 0 + lane * 2], w01 = Wr[ 1 + lane * 2];
    uint4 w10 = Wr[16 + lane * 2], w11 = Wr[17 + lane * 2];
    uint4 w20 = Wr[32 + lane * 2], w21 = Wr[33 + lane * 2];

    float bsum = 0.f, sc0 = 0.f, sc1 = 0.f, sc2 = 0.f;
    if (lane < NC) {
        bsum = u_bias[(size_t)ui * NC + lane] + v_bias[(size_t)vi * NC + lane];
        sc0 = scalars[0 * NC + lane];
        sc1 = scalars[1 * NC + lane];
        sc2 = scalars[2 * NC + lane];
    }

    float s0 = 0.f, s1 = 0.f, s2 = 0.f;
    dot8(ua0, va0, w00, w10, w20, s0, s1, s2);
    dot8(ua1, va1, w01, w11, w21, s0, s1, s2);

    // Reduce across the 8-lane group (3 steps).
    #pragma unroll
    for (int off = 4; off > 0; off >>= 1) {
        s0 += __shfl_xor(s0, off, 8);
        s1 += __shfl_xor(s1, off, 8);
        s2 += __shfl_xor(s2, off, 8);
    }

    if (lane < NC) {
        float r = s0 * sc0 + s1 * sc1 + s2 * sc2 + bsum;
        __builtin_nontemporal_store(r, out + (size_t)e * NC + lane);
    }
}

// ---- Fallback (f32 gathers) if ws too small ----
__global__ __launch_bounds__(256) void bilinear_f32_kernel(
    const float* __restrict__ u_feats, const float* __restrict__ v_feats,
    const int* __restrict__ u_idx, const int* __restrict__ v_idx,
    const float* __restrict__ W, const float* __restrict__ scalars,
    const float* __restrict__ u_bias, const float* __restrict__ v_bias,
    float* __restrict__ out, int E)
{
    const int lane = threadIdx.x & 15;
    const int grp  = threadIdx.x >> 4;
    const int e    = blockIdx.x * 16 + grp;
    if (e >= E) return;
    const int ui = u_idx[e];
    const int vi = v_idx[e];
    const float4* ur = (const float4*)(u_feats + (size_t)ui * D);
    const float4* vr = (const float4*)(v_feats + (size_t)vi * D);
    const float4* Wr = (const float4*)W;
    float4 ua0 = ur[lane*2+0], ua1 = ur[lane*2+1];
    float4 va0 = vr[lane*2+0], va1 = vr[lane*2+1];
    float4 w00 = Wr[ 0+lane*2], w01 = Wr[ 1+lane*2];
    float4 w10 = Wr[32+lane*2], w11 = Wr[33+lane*2];
    float4 w20 = Wr[64+lane*2], w21 = Wr[65+lane*2];
    float s0=0.f, s1=0.f, s2=0.f;
    #pragma unroll
    for (int k = 0; k < 4; ++k) {
        float p = (&ua0.x)[k] * (&va0.x)[k];
        s0 = fmaf(p, (&w00.x)[k], s0);
        s1 = fmaf(p, (&w10.x)[k], s1);
        s2 = fmaf(p, (&w20.x)[k], s2);
    }
    #pragma unroll
    for (int k = 0; k < 4; ++k) {
        float p = (&ua1.x)[k] * (&va1.x)[k];
        s0 = fmaf(p, (&w01.x)[k], s0);
        s1 = fmaf(p, (&w11.x)[k], s1);
        s2 = fmaf(p, (&w21.x)[k], s2);
    }
    #pragma unroll
    for (int off = 8; off > 0; off >>= 1) {
        s0 += __shfl_xor(s0, off, 16);
        s1 += __shfl_xor(s1, off, 16);
        s2 += __shfl_xor(s2, off, 16);
    }
    if (lane < NC) {
        float r = s0*scalars[0*NC+lane] + s1*scalars[1*NC+lane] + s2*scalars[2*NC+lane]
                + u_bias[(size_t)ui*NC+lane] + v_bias[(size_t)vi*NC+lane];
        out[(size_t)e*NC+lane] = r;
    }
}

extern "C" void kernel_launch(void* const* d_in, const int* in_sizes, int n_in,
                              void* d_out, int out_size, void* d_ws, size_t ws_size,
                              hipStream_t stream) {
    const float* u_feats = (const float*)d_in[0];
    const float* v_feats = (const float*)d_in[1];
    const int*   u_idx   = (const int*)d_in[2];
    const int*   v_idx   = (const int*)d_in[3];
    const float* W       = (const float*)d_in[4];
    const float* scalars = (const float*)d_in[5];
    const float* u_bias  = (const float*)d_in[6];
    const float* v_bias  = (const float*)d_in[7];
    float* out           = (float*)d_out;

    const int nu = in_sizes[0];   // NUM_USERS * 128
    const int nv = in_sizes[1];   // NUM_ITEMS * 128
    const int nw = in_sizes[4];   // 3 * 128
    const int E  = in_sizes[2];

    const size_t need = (size_t)(nu + nv + nw) * sizeof(__hip_bfloat16);
    if (ws_size >= need) {
        __hip_bfloat16* u_bf = (__hip_bfloat16*)d_ws;
        __hip_bfloat16* v_bf = u_bf + nu;
        __hip_bfloat16* W_bf = v_bf + nv;
        const int nu8 = nu / 8, nv8 = nv / 8, nw8 = nw / 8;
        const int tot = nu8 + nv8 + nw8;
        cvt_all_kernel<<<(tot + 255) / 256, 256, 0, stream>>>(
            u_feats, v_feats, W, u_bf, v_bf, W_bf, nu8, nv8, nw8);
        bilinear_bf16_kernel<<<(E + 31) / 32, 256, 0, stream>>>(
            u_bf, v_bf, W_bf, u_idx, v_idx, scalars, u_bias, v_bias, out, E);
    } else {
        bilinear_f32_kernel<<<(E + 15) / 16, 256, 0, stream>>>(
            u_feats, v_feats, u_idx, v_idx, W, scalars, u_bias, v_bias, out, E);
    }
}